// Round 1
// baseline (555.193 us; speedup 1.0000x reference)
//
#include <hip/hip_runtime.h>
#include <stdint.h>

// ---------------------------------------------------------------------------
// EISANI model: gray-encode -> 2 sparse ±1 threshold layers -> output matmul
// B=512, F=256, BITS=8 (E=2048), H=8192, C=100, K=32, THR=5
//
// Workspace layout (bytes):
//   prevT : uint32 [64][512]      @ 0         (128 KB)  encoded bits, [word][b]
//   a0T   : uint32 [256][512]     @ 131072    (512 KB)  layer0 bits,  [word][b]
//   a1T   : uint32 [256][512]     @ 655360    (512 KB)  layer1 bits (unused later)
//   w0s   : uint32 [8192][32]     @ 1179648   (1 MB)    packed synapses
//   w1s   : uint32 [8192][32]     @ 2228224   (1 MB)
//   abf   : bf16   [512][16384]   @ 3276800   (16 MB)   [a0 | a1] as bf16 0/1
//   wtb   : bf16   [112][16384]   @ 20054016  (3.5 MB)  wout transposed, bf16
// ---------------------------------------------------------------------------

#define WS_PREVT   0u
#define WS_A0T     131072u
#define WS_A1T     655360u
#define WS_W0S     1179648u
#define WS_W1S     2228224u
#define WS_ABF     3276800u
#define WS_WTB     20054016u

typedef __attribute__((ext_vector_type(8))) short short8;
typedef __attribute__((ext_vector_type(4))) float f32x4;

__global__ __launch_bounds__(256) void k_zero(float* __restrict__ out, int n) {
  int i = blockIdx.x * 256 + threadIdx.x;
  if (i < n) out[i] = 0.f;
}

// Gray-encode x (512x256 f32) into prevT[word][b] (64x512 uint32).
// tid -> (b = tid>>6, w = tid&63); word w covers features 4w..4w+3, the 8-bit
// gray code of a feature IS its bit-byte (bit j = (g>>j)&1).
__global__ __launch_bounds__(256) void k_encode(const float* __restrict__ x,
                                                uint32_t* __restrict__ prevT) {
  int tid = blockIdx.x * 256 + threadIdx.x;   // 0..32767
  int b = tid >> 6, w = tid & 63;
  float4 v = ((const float4*)x)[tid];         // 16B aligned: b*256 + w*4 floats
  float vs[4] = {v.x, v.y, v.z, v.w};
  uint32_t word = 0;
#pragma unroll
  for (int j = 0; j < 4; ++j) {
    float f = fminf(fmaxf(vs[j], 0.f), 1.f) * 255.f;
    int lv = (int)rintf(f);                   // round-half-even, matches jnp.round
    uint32_t g = (uint32_t)(lv ^ (lv >> 1)) & 0xFFu;
    word |= g << (8 * j);
  }
  prevT[(size_t)w * 512 + b] = word;
}

// Extract sparse rows: one block per row, find nonzeros (exactly the realized
// ±1 entries, nnz <= 32), pack as (col<<2) | code, code: 1=+1, 3=-1, 0=pad.
__global__ __launch_bounds__(256) void k_extract(const float* __restrict__ w,
                                                 int nvec4,
                                                 uint32_t* __restrict__ syn) {
  __shared__ uint32_t s_syn[32];
  __shared__ int s_cnt;
  int r = blockIdx.x;
  if (threadIdx.x < 32) s_syn[threadIdx.x] = 0;
  if (threadIdx.x == 0) s_cnt = 0;
  __syncthreads();
  const float4* row = (const float4*)(w + (size_t)r * (size_t)nvec4 * 4);
  for (int i = threadIdx.x; i < nvec4; i += 256) {
    float4 v = row[i];
    float vals[4] = {v.x, v.y, v.z, v.w};
#pragma unroll
    for (int j = 0; j < 4; ++j) {
      float f = vals[j];
      if (f != 0.f) {
        int slot = atomicAdd(&s_cnt, 1);
        s_syn[slot] = ((uint32_t)(i * 4 + j) << 2) | (f > 0.f ? 1u : 3u);
      }
    }
  }
  __syncthreads();
  if (threadIdx.x < 32) syn[(size_t)r * 32 + threadIdx.x] = s_syn[threadIdx.x];
}

// Convert wout (2,8192,100) f32 -> wtb[c][k] bf16 (112 x 16384), c>=100 zero.
__global__ __launch_bounds__(256) void k_wtb(const float* __restrict__ wout,
                                             unsigned short* __restrict__ wtb) {
  __shared__ unsigned short tile[32][113];
  int k0 = blockIdx.x * 32;
  for (int idx = threadIdx.x; idx < 32 * 112; idx += 256) {
    int row = idx / 112, c = idx - row * 112;
    float v = (c < 100) ? wout[(size_t)(k0 + row) * 100 + c] : 0.f;
    uint32_t u = __float_as_uint(v);
    uint32_t r = (u + 0x7FFFu + ((u >> 16) & 1u)) >> 16;   // RNE to bf16
    tile[row][c] = (unsigned short)r;
  }
  __syncthreads();
  for (int idx = threadIdx.x; idx < 32 * 112; idx += 256) {
    int c = idx >> 5, ks = idx & 31;
    wtb[(size_t)c * 16384 + k0 + ks] = tile[ks][c];
  }
}

// One sparse threshold layer. Wave lanes = 64 batch samples, h wave-uniform
// (scalar synapse loads). Block: 64 b x 128 h; grid 8 x 64 = 512 blocks.
// Writes packed bits outT[word][b] and bf16 0/1 into abf (via LDS transpose).
__global__ __launch_bounds__(256) void k_layer(const uint32_t* __restrict__ inT,
                                               const uint32_t* __restrict__ syn,
                                               uint32_t* __restrict__ outT,
                                               uint32_t* __restrict__ abf_dw,
                                               int hbase) {
  __shared__ unsigned short lds_act[64][130];   // stride 130: bank-conflict-free
  int b0 = (int)(blockIdx.x & 7) * 64;
  int h0 = (int)(blockIdx.x >> 3) * 128;
  int lane = threadIdx.x & 63;
  int wave = threadIdx.x >> 6;
  int b = b0 + lane;
  uint32_t hbits = 0;
  for (int i = 0; i < 32; ++i) {
    int h = __builtin_amdgcn_readfirstlane(h0 + wave * 32 + i);
    const uint32_t* srow = syn + (size_t)h * 32;
    int acc = 0;
#pragma unroll
    for (int k = 0; k < 32; ++k) {
      uint32_t s = srow[k];                    // wave-uniform -> s_load
      int sgn = ((int)(s << 30)) >> 30;        // +1 / -1 / 0 (pad)
      uint32_t col = s >> 2;
      uint32_t wv = inT[(size_t)(col >> 5) * 512 + b];  // coalesced, L2-hot
      int m = -(int)((wv >> (col & 31)) & 1);  // 0 or -1
      acc += (sgn & m);                        // bit ? sgn : 0
    }
    int active = (acc >= 5) ? 1 : 0;           // THR=5, sums are integers
    hbits |= (uint32_t)active << i;            // h&31 == i here
    lds_act[lane][wave * 32 + i] = active ? 0x3F80 : 0;  // bf16 1.0 / 0.0
  }
  outT[(size_t)((h0 >> 5) + wave) * 512 + b] = hbits;
  __syncthreads();
  // coalesced bf16 write: 64 b x 128 h == 64 x 64 dwords
  int dwbase = (hbase + h0) >> 1;
#pragma unroll
  for (int j = 0; j < 16; ++j) {
    int idx = (int)threadIdx.x + j * 256;      // 0..4095
    int b_sub = idx >> 6, hw = idx & 63;
    uint32_t val = ((const uint32_t*)&lds_act[b_sub][0])[hw];
    abf_dw[(size_t)(b0 + b_sub) * 8192 + dwbase + hw] = val;
  }
}

// out = abf(512x16384) @ wtb^T -> (512x100). MFMA 16x16x32 bf16,
// grid (32 mtiles, 7 ntiles, 8 k-slices), 1 wave/block, f32 atomic epilogue.
__global__ __launch_bounds__(64) void k_gemm(const unsigned short* __restrict__ abf,
                                             const unsigned short* __restrict__ wtb,
                                             float* __restrict__ out) {
  int mtile = blockIdx.x, ntile = blockIdx.y, kslice = blockIdx.z;
  int lane = threadIdx.x;
  int mn = lane & 15, kq = lane >> 4;
  const short8* aptr = (const short8*)(abf + (size_t)(mtile * 16 + mn) * 16384 +
                                       kslice * 2048 + kq * 8);
  const short8* bptr = (const short8*)(wtb + (size_t)(ntile * 16 + mn) * 16384 +
                                       kslice * 2048 + kq * 8);
  f32x4 acc = {0.f, 0.f, 0.f, 0.f};
#pragma unroll 4
  for (int s = 0; s < 64; ++s) {               // 64 k-steps of 32
    short8 af = aptr[s * 4];                   // stride 32 bf16 = 4 short8
    short8 bf = bptr[s * 4];
    acc = __builtin_amdgcn_mfma_f32_16x16x32_bf16(af, bf, acc, 0, 0, 0);
  }
  int n = ntile * 16 + mn;
  if (n < 100) {
#pragma unroll
    for (int j = 0; j < 4; ++j) {
      int row = mtile * 16 + kq * 4 + j;       // C/D: col=lane&15, row=quad*4+j
      atomicAdd(out + row * 100 + n, acc[j]);
    }
  }
}

extern "C" void kernel_launch(void* const* d_in, const int* in_sizes, int n_in,
                              void* d_out, int out_size, void* d_ws, size_t ws_size,
                              hipStream_t stream) {
  const float* x    = (const float*)d_in[0];   // (512,256)
  const float* w0   = (const float*)d_in[1];   // (8192,2048)
  const float* w1   = (const float*)d_in[2];   // (8192,8192)
  const float* wout = (const float*)d_in[3];   // (2,8192,100)
  float* out = (float*)d_out;                  // (512,100)
  uint8_t* ws = (uint8_t*)d_ws;

  uint32_t* prevT = (uint32_t*)(ws + WS_PREVT);
  uint32_t* a0T   = (uint32_t*)(ws + WS_A0T);
  uint32_t* a1T   = (uint32_t*)(ws + WS_A1T);
  uint32_t* w0s   = (uint32_t*)(ws + WS_W0S);
  uint32_t* w1s   = (uint32_t*)(ws + WS_W1S);
  unsigned short* abf = (unsigned short*)(ws + WS_ABF);
  unsigned short* wtb = (unsigned short*)(ws + WS_WTB);

  k_zero<<<200, 256, 0, stream>>>(out, 51200);
  k_encode<<<128, 256, 0, stream>>>(x, prevT);
  k_extract<<<8192, 256, 0, stream>>>(w0, 512, w0s);    // 2048 f32/row
  k_extract<<<8192, 256, 0, stream>>>(w1, 2048, w1s);   // 8192 f32/row
  k_wtb<<<512, 256, 0, stream>>>(wout, wtb);
  k_layer<<<512, 256, 0, stream>>>(prevT, w0s, a0T, (uint32_t*)abf, 0);
  k_layer<<<512, 256, 0, stream>>>(a0T, w1s, a1T, (uint32_t*)abf, 8192);
  dim3 g(32, 7, 8);
  k_gemm<<<g, 64, 0, stream>>>(abf, wtb, out);
}

// Round 3
// 524.770 us; speedup vs baseline: 1.0580x; 1.0580x over previous
//
#include <hip/hip_runtime.h>
#include <stdint.h>

// ---------------------------------------------------------------------------
// EISANI: gray-encode -> 2 sparse ±1 threshold layers (bit-packed) -> MFMA out
// B=512, F=256, BITS=8 (E=2048), H=8192, C=100, K=32, THR=5
//
// Workspace:
//   prevT : uint32 [64][512]   @ 0        (128 KB)   encoded bits [word][b]
//   a0T   : uint32 [256][512]  @ 131072   (512 KB)   layer0 bits  [word][b]
//   a1T   : uint32 [256][512]  @ 655360   (512 KB)   layer1 bits (contiguous
//                                                     with a0T -> [512][512])
//   w0s   : uint32 [8192][32]  @ 1179648  (1 MB)     packed synapses
//   w1s   : uint32 [8192][32]  @ 2228224  (1 MB)
//   wtb   : bf16   [112][16384]@ 3276800  (3.5 MB)   wout^T in bf16
// ---------------------------------------------------------------------------

#define WS_PREVT   0u
#define WS_A0T     131072u
#define WS_A1T     655360u
#define WS_W0S     1179648u
#define WS_W1S     2228224u
#define WS_WTB     3276800u

typedef __attribute__((ext_vector_type(8))) short short8;
typedef __attribute__((ext_vector_type(4))) float f32x4;
typedef __attribute__((ext_vector_type(4))) float fvec4;   // clang-native float4

// Mega front kernel. Block ranges (biggest first):
//   [0,8192)      extract w1 row bid            (2048 float4/row)
//   [8192,16384)  extract w0 row bid-8192       (512 float4/row)
//   [16384,16896) wtb transpose+bf16            (512 blocks)
//   [16896,17024) gray-encode                   (128 blocks)
//   [17024,17224) zero out                      (200 blocks)
__global__ __launch_bounds__(256) void k_front(
    const float* __restrict__ x, const float* __restrict__ w0,
    const float* __restrict__ w1, const float* __restrict__ wout,
    float* __restrict__ out, uint32_t* __restrict__ prevT,
    uint32_t* __restrict__ w0s, uint32_t* __restrict__ w1s,
    unsigned short* __restrict__ wtb) {
  __shared__ uint32_t s_syn[32];
  __shared__ int s_cnt;
  __shared__ unsigned short tile[32][113];
  int bid = blockIdx.x, tid = threadIdx.x;

  if (bid < 16384) {                       // ---- sparse extraction ----
    const float* w; uint32_t* syn; int r, n4;
    if (bid < 8192) { w = w1; syn = w1s; r = bid;        n4 = 2048; }
    else            { w = w0; syn = w0s; r = bid - 8192; n4 = 512;  }
    if (tid < 32) s_syn[tid] = 0;          // pad: col=0, code 0 (sgn=0)
    if (tid == 0) s_cnt = 0;
    __syncthreads();
    const fvec4* row = (const fvec4*)(w + (size_t)r * (size_t)n4 * 4);
    for (int i = tid; i < n4; i += 256) {
      fvec4 v = __builtin_nontemporal_load(row + i);
#pragma unroll
      for (int j = 0; j < 4; ++j) {
        float f = v[j];
        if (f != 0.f) {
          int slot = atomicAdd(&s_cnt, 1);
          s_syn[slot] = ((uint32_t)(i * 4 + j) << 2) | (f > 0.f ? 1u : 3u);
        }
      }
    }
    __syncthreads();
    if (tid < 32) syn[(size_t)r * 32 + tid] = s_syn[tid];

  } else if (bid < 16896) {                // ---- wout -> wtb (bf16, T) ----
    int k0 = (bid - 16384) * 32;
    for (int idx = tid; idx < 32 * 112; idx += 256) {
      int row = idx / 112, c = idx - row * 112;
      float v = (c < 100) ? wout[(size_t)(k0 + row) * 100 + c] : 0.f;
      uint32_t u = __float_as_uint(v);
      uint32_t r = (u + 0x7FFFu + ((u >> 16) & 1u)) >> 16;   // RNE to bf16
      tile[row][c] = (unsigned short)r;
    }
    __syncthreads();
    for (int idx = tid; idx < 32 * 112; idx += 256) {
      int c = idx >> 5, ks = idx & 31;
      wtb[(size_t)c * 16384 + k0 + ks] = tile[ks][c];
    }

  } else if (bid < 17024) {                // ---- gray encode ----
    int t = (bid - 16896) * 256 + tid;     // 0..32767
    int b = t >> 6, w = t & 63;
    fvec4 v = ((const fvec4*)x)[t];
    uint32_t word = 0;
#pragma unroll
    for (int j = 0; j < 4; ++j) {
      float f = fminf(fmaxf(v[j], 0.f), 1.f) * 255.f;
      int lv = (int)rintf(f);              // RNE, matches jnp.round
      uint32_t g = (uint32_t)(lv ^ (lv >> 1)) & 0xFFu;
      word |= g << (8 * j);
    }
    prevT[(size_t)w * 512 + b] = word;

  } else {                                 // ---- zero out ----
    int i = (bid - 17024) * 256 + tid;
    if (i < 51200) out[i] = 0.f;
  }
}

// Sparse ±1 threshold layer, LDS-staged bit table.
// Block 256 = 4 waves; lanes = 64 batch, wave handles 32 h.
// Grid 8 b-tiles x 64 h-tiles = 512 blocks. Dynamic LDS = nwords*64*4 B
// (16 KB layer0 / 64 KB layer1 -> 2 blocks/CU).
__global__ __launch_bounds__(256) void k_layer(const uint32_t* __restrict__ inT,
                                               const uint32_t* __restrict__ syn,
                                               uint32_t* __restrict__ outT,
                                               int nwords) {
  extern __shared__ uint32_t sbits[];      // [word][64 b_local]
  int tid = threadIdx.x;
  int b0 = (int)(blockIdx.x & 7) * 64;
  int h0 = (int)(blockIdx.x >> 3) * 128;
  int nvec = nwords * 16;                  // uint4 count
  for (int j = tid; j < nvec; j += 256) {  // coalesced 16B stage
    int w = j >> 4, bl = (j & 15) * 4;
    *(uint4*)&sbits[(size_t)j * 4] = *(const uint4*)&inT[(size_t)w * 512 + b0 + bl];
  }
  __syncthreads();
  int lane = tid & 63, wave = tid >> 6;
  int b = b0 + lane;
  uint32_t hbits = 0;
  for (int i = 0; i < 32; ++i) {
    int h = __builtin_amdgcn_readfirstlane(h0 + wave * 32 + i);
    const uint32_t* srow = syn + (size_t)h * 32;
    int acc = 0;
#pragma unroll
    for (int k = 0; k < 32; ++k) {
      uint32_t s = srow[k];                // wave-uniform -> s_load
      int sgn = ((int)(s << 30)) >> 30;    // +1 / -1 / 0(pad)
      uint32_t col = s >> 2;
      uint32_t wv = sbits[(col >> 5) * 64 + lane];   // 2-way LDS, free
      int m = -(int)((wv >> (col & 31)) & 1);
      acc += (sgn & m);
    }
    hbits |= (uint32_t)((acc >= 5) ? 1 : 0) << i;    // THR=5
  }
  outT[(size_t)((h0 >> 5) + wave) * 512 + b] = hbits;
}

// out = acts(512x16384 bits) @ wtb^T. A-fragments expanded from packed bits:
// k' = ks*2048 + s*32 + kq*8 + j  ->  word ks*64+s, byte kq, bit j.
// Grid (32 mtiles, 7 ntiles, 8 k-slices), 1 wave/block, atomic f32 epilogue.
__global__ __launch_bounds__(64) void k_gemm(const uint32_t* __restrict__ bitsT,
                                             const unsigned short* __restrict__ wtb,
                                             float* __restrict__ out) {
  int mtile = blockIdx.x, ntile = blockIdx.y, ks = blockIdx.z;
  int lane = threadIdx.x, mn = lane & 15, kq = lane >> 4;
  const short8* bptr = (const short8*)(wtb + (size_t)(ntile * 16 + mn) * 16384 +
                                       ks * 2048 + kq * 8);
  const uint32_t* aptr = bitsT + (size_t)(ks * 64) * 512 + mtile * 16 + mn;
  f32x4 acc = {0.f, 0.f, 0.f, 0.f};
#pragma unroll 8
  for (int s = 0; s < 64; ++s) {
    uint32_t wbits = aptr[(size_t)s * 512];          // 64B/instr, L2-hot, bcast x4
    uint32_t byte = (wbits >> (kq * 8)) & 0xFFu;
    union { short8 v; uint32_t d[4]; } a;
#pragma unroll
    for (int j = 0; j < 4; ++j) {
      a.d[j] = (((byte >> (2 * j)) & 1u) ? 0x3F80u : 0u) |
               (((byte >> (2 * j + 1)) & 1u) ? 0x3F800000u : 0u);
    }
    short8 bf = bptr[(size_t)s * 4];
    acc = __builtin_amdgcn_mfma_f32_16x16x32_bf16(a.v, bf, acc, 0, 0, 0);
  }
  int n = ntile * 16 + mn;
  if (n < 100) {
#pragma unroll
    for (int j = 0; j < 4; ++j) {
      int row = mtile * 16 + kq * 4 + j;             // C/D: col=lane&15, row=kq*4+j
      atomicAdd(out + row * 100 + n, acc[j]);
    }
  }
}

extern "C" void kernel_launch(void* const* d_in, const int* in_sizes, int n_in,
                              void* d_out, int out_size, void* d_ws, size_t ws_size,
                              hipStream_t stream) {
  const float* x    = (const float*)d_in[0];   // (512,256)
  const float* w0   = (const float*)d_in[1];   // (8192,2048)
  const float* w1   = (const float*)d_in[2];   // (8192,8192)
  const float* wout = (const float*)d_in[3];   // (2,8192,100)
  float* out = (float*)d_out;                  // (512,100)
  uint8_t* ws = (uint8_t*)d_ws;

  uint32_t* prevT = (uint32_t*)(ws + WS_PREVT);
  uint32_t* a0T   = (uint32_t*)(ws + WS_A0T);
  uint32_t* a1T   = (uint32_t*)(ws + WS_A1T);
  uint32_t* w0s   = (uint32_t*)(ws + WS_W0S);
  uint32_t* w1s   = (uint32_t*)(ws + WS_W1S);
  unsigned short* wtb = (unsigned short*)(ws + WS_WTB);

  k_front<<<17224, 256, 0, stream>>>(x, w0, w1, wout, out, prevT, w0s, w1s, wtb);
  k_layer<<<512, 256, 64 * 64 * 4, stream>>>(prevT, w0s, a0T, 64);     // 16 KB
  k_layer<<<512, 256, 256 * 64 * 4, stream>>>(a0T, w1s, a1T, 256);     // 64 KB
  dim3 g(32, 7, 8);
  k_gemm<<<g, 64, 0, stream>>>(a0T /* == bitsT[512][512] */, wtb, out);
}